// Round 1
// baseline (445.389 us; speedup 1.0000x reference)
//
#include <hip/hip_runtime.h>

// ---------------------------------------------------------------------------
// LoRA forward: out = x @ W^T + 2 * (x @ A^T) @ B^T
//   x:[4,4096,2048] f32, W:[2048,2048] f32, A:[16,2048] f32, B:[2048,16] f32
// Strategy:
//   1) W_eff = bf16(W + 2 * B @ A)          (tiny: 2048x2048x16)
//   2) Xb    = bf16(x)                      (memory-bound convert)
//   3) out   = Xb @ W_eff^T  via m97-style bf16 MFMA GEMM (fp32 accum)
// ---------------------------------------------------------------------------

typedef __bf16 bf16x8 __attribute__((ext_vector_type(8)));
typedef float  f32x4  __attribute__((ext_vector_type(4)));
typedef unsigned short u16x8 __attribute__((ext_vector_type(8)));

#define AS1C(p) ((const __attribute__((address_space(1))) void*)(p))
#define AS3(p)  ((__attribute__((address_space(3))) void*)(p))

__device__ __forceinline__ unsigned short f2bf(float f) {
  // round-to-nearest-even f32 -> bf16 (inputs are normal randoms; NaN not expected)
  unsigned int u = __float_as_uint(f);
  u += 0x7FFFu + ((u >> 16) & 1u);
  return (unsigned short)(u >> 16);
}

constexpr int M_ = 16384;   // 4 * 4096
constexpr int N_ = 2048;    // D_out
constexpr int K_ = 2048;    // D_in
constexpr int R_ = 16;
constexpr float SCALING = 2.0f;  // 32/16

constexpr int BM = 128, BN = 128, BK = 32;

// ---- kernel 1: x f32 -> bf16, 8 elems/thread --------------------------------
__global__ __launch_bounds__(256) void cvt_kernel(const float* __restrict__ in,
                                                  unsigned short* __restrict__ out) {
  size_t i = (size_t)blockIdx.x * blockDim.x + threadIdx.x;
  const float4* p = (const float4*)in;
  float4 a = p[2 * i];
  float4 b = p[2 * i + 1];
  u16x8 o;
  o[0] = f2bf(a.x); o[1] = f2bf(a.y); o[2] = f2bf(a.z); o[3] = f2bf(a.w);
  o[4] = f2bf(b.x); o[5] = f2bf(b.y); o[6] = f2bf(b.z); o[7] = f2bf(b.w);
  ((u16x8*)out)[i] = o;
}

// ---- kernel 2: W_eff = bf16(W + 2 * B @ A), [N,K] row-major -----------------
__global__ __launch_bounds__(256) void weff_kernel(const float* __restrict__ W,
                                                   const float* __restrict__ A,
                                                   const float* __restrict__ Bl,
                                                   unsigned short* __restrict__ out) {
  int idx = blockIdx.x * blockDim.x + threadIdx.x;  // over N_*K_
  int o = idx >> 11;        // / 2048
  int d = idx & 2047;       // % 2048
  float acc = W[idx];
#pragma unroll
  for (int r = 0; r < R_; ++r)
    acc = fmaf(SCALING * Bl[o * R_ + r], A[r * K_ + d], acc);
  out[idx] = f2bf(acc);
}

// ---- kernel 3: C[M,N] = Xb[M,K] @ W_eff[N,K]^T  (bf16 in, f32 out) ----------
// 256 threads = 4 waves; block tile 128x128; wave tile 64x64 (4x4 MFMA 16x16x32)
__global__ __launch_bounds__(256) void gemm_kernel(const unsigned short* __restrict__ X,
                                                   const unsigned short* __restrict__ W,
                                                   float* __restrict__ C) {
  __shared__ __align__(16) unsigned short As[BM * BK];  // 8 KB, row-major [128][32]
  __shared__ __align__(16) unsigned short Bs[BN * BK];  // 8 KB

  const int tid  = threadIdx.x;
  const int wave = tid >> 6;
  const int lane = tid & 63;

  const int bm = blockIdx.y * BM;
  const int bn = blockIdx.x * BN;

  const int wm = (wave & 1) * 64;   // wave's row offset in block tile
  const int wn = (wave >> 1) * 64;  // wave's col offset

  f32x4 acc[4][4] = {};

  // staging: each wave fills 32 rows of each tile with 2 global_load_lds calls
  // (64 lanes x 16B = 1024 B = 16 rows of 64 B). lane L -> row L/4, seg L%4.
  const int rq = lane >> 2;  // 0..15
  const int sg = lane & 3;   // 0..3 (16B segments)

  const unsigned short* xg0 = X + (size_t)(bm + wave * 32 + rq) * K_ + sg * 8;
  const unsigned short* xg1 = X + (size_t)(bm + wave * 32 + 16 + rq) * K_ + sg * 8;
  const unsigned short* wg0 = W + (size_t)(bn + wave * 32 + rq) * K_ + sg * 8;
  const unsigned short* wg1 = W + (size_t)(bn + wave * 32 + 16 + rq) * K_ + sg * 8;

  unsigned short* la0 = &As[(wave * 32) * BK];        // wave-uniform LDS bases
  unsigned short* la1 = &As[(wave * 32 + 16) * BK];
  unsigned short* lb0 = &Bs[(wave * 32) * BK];
  unsigned short* lb1 = &Bs[(wave * 32 + 16) * BK];

  // MFMA fragment addressing: A[m = lane&15][k = (lane>>4)*8 + j]
  const int fm = lane & 15;
  const int fk = (lane >> 4) * 8;

  for (int k0 = 0; k0 < K_; k0 += BK) {
    __builtin_amdgcn_global_load_lds(AS1C(xg0 + k0), AS3(la0), 16, 0, 0);
    __builtin_amdgcn_global_load_lds(AS1C(xg1 + k0), AS3(la1), 16, 0, 0);
    __builtin_amdgcn_global_load_lds(AS1C(wg0 + k0), AS3(lb0), 16, 0, 0);
    __builtin_amdgcn_global_load_lds(AS1C(wg1 + k0), AS3(lb1), 16, 0, 0);
    __syncthreads();

    bf16x8 af[4], bf[4];
#pragma unroll
    for (int i = 0; i < 4; ++i)
      af[i] = *(const bf16x8*)&As[(wm + i * 16 + fm) * BK + fk];
#pragma unroll
    for (int j = 0; j < 4; ++j)
      bf[j] = *(const bf16x8*)&Bs[(wn + j * 16 + fm) * BK + fk];

#pragma unroll
    for (int i = 0; i < 4; ++i)
#pragma unroll
      for (int j = 0; j < 4; ++j)
        acc[i][j] = __builtin_amdgcn_mfma_f32_16x16x32_bf16(af[i], bf[j], acc[i][j], 0, 0, 0);

    __syncthreads();
  }

  // epilogue: C/D layout col = lane&15, row = (lane>>4)*4 + r
  const int r0   = (lane >> 4) * 4;
  const int col0 = lane & 15;
#pragma unroll
  for (int i = 0; i < 4; ++i) {
#pragma unroll
    for (int j = 0; j < 4; ++j) {
      size_t base = (size_t)(bm + wm + i * 16 + r0) * N_ + (size_t)(bn + wn + j * 16 + col0);
#pragma unroll
      for (int r = 0; r < 4; ++r)
        C[base + (size_t)r * N_] = acc[i][j][r];
    }
  }
}

extern "C" void kernel_launch(void* const* d_in, const int* in_sizes, int n_in,
                              void* d_out, int out_size, void* d_ws, size_t ws_size,
                              hipStream_t stream) {
  const float* x  = (const float*)d_in[0];  // [4,4096,2048]
  const float* W  = (const float*)d_in[1];  // [2048,2048]
  const float* A  = (const float*)d_in[2];  // [16,2048]
  const float* Bl = (const float*)d_in[3];  // [2048,16]
  float* out = (float*)d_out;               // [4,4096,2048] f32

  // workspace layout: Xb (M*K bf16 = 64 MB) | W_eff (N*K bf16 = 8 MB)
  unsigned short* Xb   = (unsigned short*)d_ws;
  unsigned short* Weff = Xb + (size_t)M_ * K_;

  // 1) convert x to bf16: 33.5M elems, 8/thread
  cvt_kernel<<<(M_ * (size_t)K_) / 8 / 256, 256, 0, stream>>>(x, Xb);

  // 2) fold LoRA into weight
  weff_kernel<<<(N_ * K_) / 256, 256, 0, stream>>>(W, A, Bl, Weff);

  // 3) main GEMM
  dim3 grid(N_ / BN, M_ / BM);  // 16 x 128 = 2048 blocks
  gemm_kernel<<<grid, 256, 0, stream>>>(Xb, Weff, out);
}